// Round 8
// baseline (572.368 us; speedup 1.0000x reference)
//
#include <hip/hip_runtime.h>

#define D   1024
#define S   4096
#define NB  16
#define NH  16
#define NSC 16   // tpart strips of 256 rows

using bf16x8 = __attribute__((ext_vector_type(8))) short;
using f32x4  = __attribute__((ext_vector_type(4))) float;

__device__ __forceinline__ short f2bf(float f) {
    unsigned int u = __float_as_uint(f);
    u += 0x7fffu + ((u >> 16) & 1u);   // RNE
    return (short)(u >> 16);
}
__device__ __forceinline__ float bf2f(unsigned short u) {
    return __uint_as_float(((unsigned int)u) << 16);
}
__device__ __forceinline__ float elu1(float x) {
    return x > 0.f ? x + 1.f : __expf(x);   // elu(x)+1
}

// ---------------- y (f32) -> ybf (bf16), m13 pattern: 16B loads x2 + 16B store, unrolled ----------------
__global__ __launch_bounds__(256) void ybf_kernel(const float* __restrict__ y,
        unsigned short* __restrict__ ybf)
{
    const size_t tid    = (size_t)blockIdx.x * 256 + threadIdx.x;  // 0..524287
    const size_t stride = (size_t)2048 * 256;                      // total threads
    // total elems = 67,108,864 = 524288 threads * 8 elems * 16 iters
#pragma unroll 4
    for (int it = 0; it < 16; ++it) {
        const size_t e0 = (tid + (size_t)it * stride) * 8;
        const float4 v0 = *reinterpret_cast<const float4*>(y + e0);
        const float4 v1 = *reinterpret_cast<const float4*>(y + e0 + 4);
        bf16x8 p;
        p[0] = f2bf(v0.x); p[1] = f2bf(v0.y); p[2] = f2bf(v0.z); p[3] = f2bf(v0.w);
        p[4] = f2bf(v1.x); p[5] = f2bf(v1.y); p[6] = f2bf(v1.z); p[7] = f2bf(v1.w);
        *reinterpret_cast<bf16x8*>(ybf + e0) = p;
    }
}

// ---------------- fused small prep: phiq (blocks 0..255) | wkt (blocks 256..1279) ----------------
__global__ __launch_bounds__(256) void prep2_kernel(
        const float* __restrict__ x, const float* __restrict__ Wq,
        const float* __restrict__ bq, float* __restrict__ phiq,
        const float* __restrict__ Wk, unsigned short* __restrict__ WkT)
{
    const int bid = blockIdx.x;
    const int t   = threadIdx.x;
    __shared__ float smemf[D];
    __shared__ float rnum[256];
    __shared__ float tile[32][33];

    if (bid < 256) {
        // ---- phiq: 16 o-chunks x 16 b ----
        const int b  = bid >> 4;
        const int o0 = (bid & 15) * 64;
        const int ol = t & 63, jq = t >> 6;
        for (int i = t; i < D; i += 256) smemf[i] = x[b * D + i];
        __syncthreads();
        float acc = 0.f;
        const int o = o0 + ol;
        for (int j = jq * 256; j < jq * 256 + 256; ++j)
            acc = fmaf(smemf[j], Wq[(size_t)j * D + o], acc);
        rnum[t] = acc;
        __syncthreads();
        if (t < 64) {
            float s = rnum[t] + rnum[64 + t] + rnum[128 + t] + rnum[192 + t];
            phiq[b * D + o0 + t] = elu1(s + bq[o0 + t]);
        }
    } else {
        // ---- wkt: WkT[o][j] = bf16(Wk[j][o]), 32x32 tiles ----
        const int b3 = bid - 256;
        const int j0 = (b3 >> 5) * 32, o0 = (b3 & 31) * 32;
        const int tx = t & 31, ty = t >> 5;
#pragma unroll
        for (int r = 0; r < 4; ++r)
            tile[ty + r * 8][tx] = Wk[(size_t)(j0 + ty + r * 8) * D + o0 + tx];
        __syncthreads();
#pragma unroll
        for (int r = 0; r < 4; ++r) {
            const int o = o0 + ty + r * 8;
            WkT[(size_t)o * D + j0 + tx] = (unsigned short)f2bf(tile[tx][ty + r * 8]);
        }
    }
}

// ---------------- fused K-projection + phi + phi_q reduction -> w[b,h,s] ----------------
// R3-proven: 128x256 tile, BK=64, 4 waves 2x2 (each 64x128 = 4x8 frags), XOR-swizzled
// LDS via pre-swizzled global_load_lds source, XCD-chunked grid, nt innermost.
__global__ __launch_bounds__(256, 2) void kgemm_kernel(
        const unsigned short* __restrict__ ybf, const unsigned short* __restrict__ WkT,
        const float* __restrict__ phiq, const float* __restrict__ bk,
        float* __restrict__ wbuf)
{
    const int bid = blockIdx.x;
    const int wg  = (bid & 7) * 256 + (bid >> 3);   // XCD-chunked
    const int mt  = wg >> 2;           // 0..511 : A-strip (nt innermost for L2 reuse)
    const int nt  = wg & 3;            // 0..3
    const int b   = mt >> 5;
    const int s0  = (mt & 31) << 7;
    const int n0  = nt << 8;           // 256-col panel
    const int t   = threadIdx.x;
    const int wv  = t >> 6;
    const int l   = t & 63;
    const int wr  = wv >> 1, wc = wv & 1;
    const int l15 = l & 15, l16 = l >> 4;

    __shared__ short Al[128 * 64];   // 16 KB
    __shared__ short Bl[256 * 64];   // 32 KB

    f32x4 acc[4][8] = {};

    const unsigned short* yb = ybf + (size_t)(b * S + s0) * D;

    for (int kt = 0; kt < D / 64; ++kt) {
        const int k0 = kt * 64;
#pragma unroll
        for (int i = 0; i < 4; ++i) {
            const int slot0 = i * 256 + wv * 64;
            const int slot  = slot0 + l;
            const int row   = slot >> 3;
            const int ke    = ((slot & 7) ^ (row & 7)) << 3;
            __builtin_amdgcn_global_load_lds(
                (const __attribute__((address_space(1))) unsigned int*)(yb + (size_t)row * D + k0 + ke),
                (__attribute__((address_space(3))) unsigned int*)(&Al[slot0 * 8]),
                16, 0, 0);
        }
#pragma unroll
        for (int i = 0; i < 8; ++i) {
            const int slot0 = i * 256 + wv * 64;
            const int slot  = slot0 + l;
            const int nrow  = slot >> 3;
            const int ke    = ((slot & 7) ^ (nrow & 7)) << 3;
            __builtin_amdgcn_global_load_lds(
                (const __attribute__((address_space(1))) unsigned int*)(WkT + (size_t)(n0 + nrow) * D + k0 + ke),
                (__attribute__((address_space(3))) unsigned int*)(&Bl[slot0 * 8]),
                16, 0, 0);
        }
        __syncthreads();
#pragma unroll
        for (int kk = 0; kk < 2; ++kk) {
            bf16x8 af[4], bfr[8];
            const int ks = (kk << 2) + l16;
#pragma unroll
            for (int m = 0; m < 4; ++m) {
                const int row = wr * 64 + m * 16 + l15;
                af[m] = *reinterpret_cast<const bf16x8*>(&Al[row * 64 + ((ks ^ (row & 7)) << 3)]);
            }
#pragma unroll
            for (int n = 0; n < 8; ++n) {
                const int row = wc * 128 + n * 16 + l15;
                bfr[n] = *reinterpret_cast<const bf16x8*>(&Bl[row * 64 + ((ks ^ (row & 7)) << 3)]);
            }
#pragma unroll
            for (int m = 0; m < 4; ++m)
#pragma unroll
                for (int n = 0; n < 8; ++n)
                    acc[m][n] = __builtin_amdgcn_mfma_f32_16x16x32_bf16(af[m], bfr[n], acc[m][n], 0, 0, 0);
        }
        __syncthreads();
    }

    // epilogue: wave covers 2 heads (cols n0+wc*128 .. +127)
    const int h0 = (n0 >> 6) + wc * 2;
    float pq[8], bkv[8];
#pragma unroll
    for (int n = 0; n < 8; ++n) {
        const int col = n0 + wc * 128 + n * 16 + l15;
        pq[n]  = phiq[b * D + col];
        bkv[n] = bk[col];
    }
#pragma unroll
    for (int m = 0; m < 4; ++m) {
#pragma unroll
        for (int j = 0; j < 4; ++j) {
            float rs0 = 0.f, rs1 = 0.f;
#pragma unroll
            for (int n = 0; n < 4; ++n) {
                rs0 += elu1(acc[m][n][j] + bkv[n]) * pq[n];
                rs1 += elu1(acc[m][n + 4][j] + bkv[n + 4]) * pq[n + 4];
            }
            rs0 += __shfl_xor(rs0, 1); rs1 += __shfl_xor(rs1, 1);
            rs0 += __shfl_xor(rs0, 2); rs1 += __shfl_xor(rs1, 2);
            rs0 += __shfl_xor(rs0, 4); rs1 += __shfl_xor(rs1, 4);
            rs0 += __shfl_xor(rs0, 8); rs1 += __shfl_xor(rs1, 8);
            if (l15 == 0) {
                const int row = s0 + wr * 64 + m * 16 + l16 * 4 + j;
                wbuf[(size_t)(b * NH + h0) * S + row]     = rs0;
                wbuf[(size_t)(b * NH + h0 + 1) * S + row] = rs1;
            }
        }
    }
}

// ---------------- t_part[sc][b][h][j] = sum_{s in chunk} w[b,h,s] * ybf[b,s,j] ----------------
__global__ __launch_bounds__(256) void tpart_kernel(
        const unsigned short* __restrict__ ybf, const float* __restrict__ wbuf,
        float* __restrict__ tpart)
{
    const int sc = blockIdx.x;   // 0..15 (256 s each)
    const int b  = blockIdx.y;
    const int t  = threadIdx.x;
    const int s0 = sc * 256;
    __shared__ float wl[16 * 256];
#pragma unroll
    for (int r = 0; r < 16; ++r) {
        const int lin = r * 256 + t;
        wl[lin] = wbuf[(size_t)(b * NH + (lin >> 8)) * S + s0 + (lin & 255)];
    }
    __syncthreads();
    float acc[16][4] = {};
    const unsigned short* yb = ybf + (size_t)(b * S + s0) * D + t * 4;
    for (int si = 0; si < 256; ++si) {
        const short4 v4 = *reinterpret_cast<const short4*>(yb + (size_t)si * D);
        const float vx = bf2f((unsigned short)v4.x);
        const float vy = bf2f((unsigned short)v4.y);
        const float vz = bf2f((unsigned short)v4.z);
        const float vw = bf2f((unsigned short)v4.w);
#pragma unroll
        for (int hh = 0; hh < 16; ++hh) {
            const float wv = wl[hh * 256 + si];
            acc[hh][0] = fmaf(wv, vx, acc[hh][0]);
            acc[hh][1] = fmaf(wv, vy, acc[hh][1]);
            acc[hh][2] = fmaf(wv, vz, acc[hh][2]);
            acc[hh][3] = fmaf(wv, vw, acc[hh][3]);
        }
    }
    float* tp = tpart + ((size_t)(sc * NB + b) * NH) * D + t * 4;
#pragma unroll
    for (int hh = 0; hh < 16; ++hh) {
        float4 o;
        o.x = acc[hh][0]; o.y = acc[hh][1]; o.z = acc[hh][2]; o.w = acc[hh][3];
        *reinterpret_cast<float4*>(tp + hh * D) = o;
    }
}

// ---------------- ctx[b,h*64+v] = (t@Wv[:,hcol] + denom*bv)/(denom+eps); absorbs tred ----------------
__global__ __launch_bounds__(256) void ctx_kernel(
        const float* __restrict__ wbuf, const float* __restrict__ tpart,
        const float* __restrict__ Wv, const float* __restrict__ bv,
        float* __restrict__ ctx)
{
    const int b = blockIdx.x >> 4, h = blockIdx.x & 15;
    const int t = threadIdx.x;
    __shared__ float t_l[D];
    __shared__ float rnum[256];
    __shared__ float rden[4];
    // denom = sum_s w
    const float* wr_ = wbuf + (size_t)(b * NH + h) * S;
    float dp = 0.f;
    for (int i = t; i < S; i += 256) dp += wr_[i];
#pragma unroll
    for (int off = 1; off < 64; off <<= 1) dp += __shfl_xor(dp, off);
    if ((t & 63) == 0) rden[t >> 6] = dp;
    // t = strip-sum of tpart
    float4 a = {0.f, 0.f, 0.f, 0.f};
    for (int sc = 0; sc < NSC; ++sc) {
        const float4 v = *reinterpret_cast<const float4*>(
            tpart + ((size_t)((sc * NB + b) * NH + h)) * D + t * 4);
        a.x += v.x; a.y += v.y; a.z += v.z; a.w += v.w;
    }
    *reinterpret_cast<float4*>(&t_l[t * 4]) = a;
    __syncthreads();
    const float denom = rden[0] + rden[1] + rden[2] + rden[3];
    const int v = t & 63, jq = t >> 6;
    float np = 0.f;
    for (int j = jq * 256; j < jq * 256 + 256; ++j)
        np = fmaf(t_l[j], Wv[(size_t)j * D + h * 64 + v], np);
    rnum[t] = np;
    __syncthreads();
    if (t < 64) {
        float num = rnum[t] + rnum[64 + t] + rnum[128 + t] + rnum[192 + t];
        num += denom * bv[h * 64 + t];
        ctx[(size_t)b * D + h * 64 + t] = num / (denom + 1e-6f);
    }
}

// ---------------- out = ctx @ Wo + bo (256 blocks, j-split + LDS reduce) ----------------
__global__ __launch_bounds__(256) void out_kernel(
        const float* __restrict__ ctx, const float* __restrict__ Wo,
        const float* __restrict__ bo, float* __restrict__ out)
{
    const int b  = blockIdx.y;
    const int o0 = blockIdx.x * 64;
    const int t  = threadIdx.x;
    const int ol = t & 63, jq = t >> 6;
    __shared__ float cl[D];
    __shared__ float rnum[256];
    for (int i = t; i < D; i += 256) cl[i] = ctx[(size_t)b * D + i];
    __syncthreads();
    float acc = 0.f;
    const int o = o0 + ol;
    for (int j = jq * 256; j < jq * 256 + 256; ++j)
        acc = fmaf(cl[j], Wo[(size_t)j * D + o], acc);
    rnum[t] = acc;
    __syncthreads();
    if (t < 64) {
        float s = rnum[t] + rnum[64 + t] + rnum[128 + t] + rnum[192 + t];
        out[(size_t)b * D + o0 + t] = s + bo[o0 + t];
    }
}

extern "C" void kernel_launch(void* const* d_in, const int* in_sizes, int n_in,
                              void* d_out, int out_size, void* d_ws, size_t ws_size,
                              hipStream_t stream) {
    const float* y  = (const float*)d_in[0];
    const float* x  = (const float*)d_in[1];
    const float* Wq = (const float*)d_in[2];
    const float* bq = (const float*)d_in[3];
    const float* Wk = (const float*)d_in[4];
    const float* bk = (const float*)d_in[5];
    const float* Wv = (const float*)d_in[6];
    const float* bv = (const float*)d_in[7];
    const float* Wo = (const float*)d_in[8];
    const float* bo = (const float*)d_in[9];
    float* out = (float*)d_out;

    char* ws = (char*)d_ws;
    size_t off = 0;
    unsigned short* ybf  = (unsigned short*)(ws + off); off += (size_t)NB * S * D * 2;        // 128 MB
    unsigned short* WkT  = (unsigned short*)(ws + off); off += (size_t)D * D * 2;             // 2 MB
    float*          phiq = (float*)(ws + off);          off += (size_t)NB * D * 4;            // 64 KB
    float*          wbuf = (float*)(ws + off);          off += (size_t)NB * NH * S * 4;       // 4 MB
    float*          tpart= (float*)(ws + off);          off += (size_t)NSC * NB * NH * D * 4; // 16 MB
    float*          ctx  = (float*)(ws + off);          off += (size_t)NB * D * 4;            // 64 KB

    ybf_kernel  <<<2048, 256, 0, stream>>>(y, ybf);
    prep2_kernel<<<1280, 256, 0, stream>>>(x, Wq, bq, phiq, Wk, WkT);
    kgemm_kernel<<<2048, 256, 0, stream>>>(ybf, WkT, phiq, bk, wbuf);
    tpart_kernel<<<dim3(NSC, NB), 256, 0, stream>>>(ybf, wbuf, tpart);
    ctx_kernel  <<<256, 256, 0, stream>>>(wbuf, tpart, Wv, bv, ctx);
    out_kernel  <<<dim3(16, NB), 256, 0, stream>>>(ctx, Wo, bo, out);
}

// Round 9
// 377.847 us; speedup vs baseline: 1.5148x; 1.5148x over previous
//
#include <hip/hip_runtime.h>

#define D   1024
#define S   4096
#define NB  16
#define NH  16
#define NSC 16

using bf16x8 = __attribute__((ext_vector_type(8))) short;
using f32x4  = __attribute__((ext_vector_type(4))) float;

__device__ __forceinline__ short f2bf(float f) {
    unsigned int u = __float_as_uint(f);
    u += 0x7fffu + ((u >> 16) & 1u);   // RNE
    return (short)(u >> 16);
}
__device__ __forceinline__ float bf2f(unsigned short u) {
    return __uint_as_float(((unsigned int)u) << 16);
}
__device__ __forceinline__ float elu1(float x) {
    return x > 0.f ? x + 1.f : __expf(x);   // elu(x)+1
}

// ---------------- y (f32) -> ybf (bf16): m13 pattern, deep MLP via unroll ----------------
// 524288 threads x 16 iters x 8 elems = 67,108,864 = NB*S*D. 16B loads + 16B stores;
// unroll 8 keeps ~16 float4 loads in flight per wave (R7 evidence: rolled loop was
// 1.3 TB/s, VALUBusy 4% -> latency-bound on a single outstanding load).
__global__ __launch_bounds__(256) void ybf_kernel(const float* __restrict__ y,
        unsigned short* __restrict__ ybf)
{
    const size_t tid    = (size_t)blockIdx.x * 256 + threadIdx.x;  // 0..524287
    const size_t stride = (size_t)2048 * 256;                      // 524288
#pragma unroll 8
    for (int it = 0; it < 16; ++it) {
        const size_t e0 = (tid + (size_t)it * stride) * 8;
        const float4 v0 = *reinterpret_cast<const float4*>(y + e0);
        const float4 v1 = *reinterpret_cast<const float4*>(y + e0 + 4);
        bf16x8 p;
        p[0] = f2bf(v0.x); p[1] = f2bf(v0.y); p[2] = f2bf(v0.z); p[3] = f2bf(v0.w);
        p[4] = f2bf(v1.x); p[5] = f2bf(v1.y); p[6] = f2bf(v1.z); p[7] = f2bf(v1.w);
        *reinterpret_cast<bf16x8*>(ybf + e0) = p;
    }
}

// ---------------- phi_q = elu(x @ Wq + bq) + 1 : [16,1024] ----------------
__global__ __launch_bounds__(256) void phiq_kernel(const float* __restrict__ x,
        const float* __restrict__ Wq, const float* __restrict__ bq,
        float* __restrict__ phiq)
{
    const int b = blockIdx.y;
    const int o = blockIdx.x * 256 + threadIdx.x;
    __shared__ float xl[D];
    for (int i = threadIdx.x; i < D; i += 256) xl[i] = x[b * D + i];
    __syncthreads();
    float acc = bq[o];
    for (int j = 0; j < D; ++j) acc = fmaf(xl[j], Wq[(size_t)j * D + o], acc);
    phiq[b * D + o] = elu1(acc);
}

// ---------------- WkT[o][j] = bf16(Wk[j][o]) ----------------
__global__ __launch_bounds__(256) void wkt_kernel(const float* __restrict__ Wk,
        unsigned short* __restrict__ WkT)
{
    __shared__ float tile[32][33];
    const int tx = threadIdx.x & 31, ty = threadIdx.x >> 5;
    const int j0 = blockIdx.y * 32, o0 = blockIdx.x * 32;
#pragma unroll
    for (int r = 0; r < 4; ++r)
        tile[ty + r * 8][tx] = Wk[(size_t)(j0 + ty + r * 8) * D + o0 + tx];
    __syncthreads();
#pragma unroll
    for (int r = 0; r < 4; ++r) {
        const int o = o0 + ty + r * 8;
        WkT[(size_t)o * D + j0 + tx] = (unsigned short)f2bf(tile[tx][ty + r * 8]);
    }
}

// ---------------- fused K-projection + phi + phi_q reduction -> w[b,h,s] ----------------
// Tile 128x256, BK=64, 4 waves 2x2 (each 64x128 = 4x8 frags). A/B staged via
// global_load_lds width=16 with column-slot XOR swizzle (pre-swizzled source).
// Grid 2048 1D: wg=(bid&7)*256+(bid>>3) -> XCD-chunked; mt=wg>>2, nt=wg&3 innermost.
__global__ __launch_bounds__(256, 2) void kgemm_kernel(
        const unsigned short* __restrict__ ybf, const unsigned short* __restrict__ WkT,
        const float* __restrict__ phiq, const float* __restrict__ bk,
        float* __restrict__ wbuf)
{
    const int bid = blockIdx.x;
    const int wg  = (bid & 7) * 256 + (bid >> 3);
    const int mt  = wg >> 2;           // 0..511
    const int nt  = wg & 3;            // 0..3
    const int b   = mt >> 5;
    const int s0  = (mt & 31) << 7;
    const int n0  = nt << 8;           // 256-col panel
    const int t   = threadIdx.x;
    const int wv  = t >> 6;
    const int l   = t & 63;
    const int wr  = wv >> 1, wc = wv & 1;
    const int l15 = l & 15, l16 = l >> 4;

    __shared__ short Al[128 * 64];   // 16 KB
    __shared__ short Bl[256 * 64];   // 32 KB

    f32x4 acc[4][8] = {};

    const unsigned short* yb = ybf + (size_t)(b * S + s0) * D;

    for (int kt = 0; kt < D / 64; ++kt) {
        const int k0 = kt * 64;
#pragma unroll
        for (int i = 0; i < 4; ++i) {
            const int slot0 = i * 256 + wv * 64;
            const int slot  = slot0 + l;
            const int row   = slot >> 3;
            const int ke    = ((slot & 7) ^ (row & 7)) << 3;
            __builtin_amdgcn_global_load_lds(
                (const __attribute__((address_space(1))) unsigned int*)(yb + (size_t)row * D + k0 + ke),
                (__attribute__((address_space(3))) unsigned int*)(&Al[slot0 * 8]),
                16, 0, 0);
        }
#pragma unroll
        for (int i = 0; i < 8; ++i) {
            const int slot0 = i * 256 + wv * 64;
            const int slot  = slot0 + l;
            const int nrow  = slot >> 3;
            const int ke    = ((slot & 7) ^ (nrow & 7)) << 3;
            __builtin_amdgcn_global_load_lds(
                (const __attribute__((address_space(1))) unsigned int*)(WkT + (size_t)(n0 + nrow) * D + k0 + ke),
                (__attribute__((address_space(3))) unsigned int*)(&Bl[slot0 * 8]),
                16, 0, 0);
        }
        __syncthreads();
#pragma unroll
        for (int kk = 0; kk < 2; ++kk) {
            bf16x8 af[4], bfr[8];
            const int ks = (kk << 2) + l16;
#pragma unroll
            for (int m = 0; m < 4; ++m) {
                const int row = wr * 64 + m * 16 + l15;
                af[m] = *reinterpret_cast<const bf16x8*>(&Al[row * 64 + ((ks ^ (row & 7)) << 3)]);
            }
#pragma unroll
            for (int n = 0; n < 8; ++n) {
                const int row = wc * 128 + n * 16 + l15;
                bfr[n] = *reinterpret_cast<const bf16x8*>(&Bl[row * 64 + ((ks ^ (row & 7)) << 3)]);
            }
#pragma unroll
            for (int m = 0; m < 4; ++m)
#pragma unroll
                for (int n = 0; n < 8; ++n)
                    acc[m][n] = __builtin_amdgcn_mfma_f32_16x16x32_bf16(af[m], bfr[n], acc[m][n], 0, 0, 0);
        }
        __syncthreads();
    }

    // epilogue: wave covers 2 heads (cols n0+wc*128 .. +127)
    const int h0 = (n0 >> 6) + wc * 2;
    float pq[8], bkv[8];
#pragma unroll
    for (int n = 0; n < 8; ++n) {
        const int col = n0 + wc * 128 + n * 16 + l15;
        pq[n]  = phiq[b * D + col];
        bkv[n] = bk[col];
    }
#pragma unroll
    for (int m = 0; m < 4; ++m) {
#pragma unroll
        for (int j = 0; j < 4; ++j) {
            float rs0 = 0.f, rs1 = 0.f;
#pragma unroll
            for (int n = 0; n < 4; ++n) {
                rs0 += elu1(acc[m][n][j] + bkv[n]) * pq[n];
                rs1 += elu1(acc[m][n + 4][j] + bkv[n + 4]) * pq[n + 4];
            }
            rs0 += __shfl_xor(rs0, 1); rs1 += __shfl_xor(rs1, 1);
            rs0 += __shfl_xor(rs0, 2); rs1 += __shfl_xor(rs1, 2);
            rs0 += __shfl_xor(rs0, 4); rs1 += __shfl_xor(rs1, 4);
            rs0 += __shfl_xor(rs0, 8); rs1 += __shfl_xor(rs1, 8);
            if (l15 == 0) {
                const int row = s0 + wr * 64 + m * 16 + l16 * 4 + j;
                wbuf[(size_t)(b * NH + h0) * S + row]     = rs0;
                wbuf[(size_t)(b * NH + h0 + 1) * S + row] = rs1;
            }
        }
    }
}

// ---------------- t_part[sc][b][h][j] = sum_{s in chunk} w[b,h,s] * ybf[b,s,j] ----------------
__global__ __launch_bounds__(256) void tpart_kernel(
        const unsigned short* __restrict__ ybf, const float* __restrict__ wbuf,
        float* __restrict__ tpart)
{
    const int sc = blockIdx.x;   // 0..15 (256 s each)
    const int b  = blockIdx.y;
    const int t  = threadIdx.x;
    const int s0 = sc * 256;
    __shared__ float wl[16 * 256];
#pragma unroll
    for (int r = 0; r < 16; ++r) {
        const int lin = r * 256 + t;
        wl[lin] = wbuf[(size_t)(b * NH + (lin >> 8)) * S + s0 + (lin & 255)];
    }
    __syncthreads();
    float acc[16][4] = {};
    const unsigned short* yb = ybf + (size_t)(b * S + s0) * D + t * 4;
    for (int si = 0; si < 256; ++si) {
        const short4 v4 = *reinterpret_cast<const short4*>(yb + (size_t)si * D);
        const float vx = bf2f((unsigned short)v4.x);
        const float vy = bf2f((unsigned short)v4.y);
        const float vz = bf2f((unsigned short)v4.z);
        const float vw = bf2f((unsigned short)v4.w);
#pragma unroll
        for (int hh = 0; hh < 16; ++hh) {
            const float wv = wl[hh * 256 + si];
            acc[hh][0] = fmaf(wv, vx, acc[hh][0]);
            acc[hh][1] = fmaf(wv, vy, acc[hh][1]);
            acc[hh][2] = fmaf(wv, vz, acc[hh][2]);
            acc[hh][3] = fmaf(wv, vw, acc[hh][3]);
        }
    }
    float* tp = tpart + ((size_t)(sc * NB + b) * NH) * D + t * 4;
#pragma unroll
    for (int hh = 0; hh < 16; ++hh) {
        float4 o;
        o.x = acc[hh][0]; o.y = acc[hh][1]; o.z = acc[hh][2]; o.w = acc[hh][3];
        *reinterpret_cast<float4*>(tp + hh * D) = o;
    }
}

__global__ __launch_bounds__(256) void tred_kernel(const float* __restrict__ tpart,
        float* __restrict__ tbuf)
{
    const int idx = blockIdx.x * 256 + threadIdx.x;   // 0..262143
    float s = 0.f;
#pragma unroll
    for (int sc = 0; sc < NSC; ++sc) s += tpart[(size_t)sc * (NB * NH * D) + idx];
    tbuf[idx] = s;
}

// ---------------- ctx[b, h*64+v] = (t[b,h,:]@Wv[:,h*64+v] + denom*bv) / (denom+eps) ----------------
__global__ __launch_bounds__(256) void ctx_kernel(
        const float* __restrict__ wbuf, const float* __restrict__ tbuf,
        const float* __restrict__ Wv, const float* __restrict__ bv,
        float* __restrict__ ctx)
{
    const int b = blockIdx.x >> 4, h = blockIdx.x & 15;
    const int t = threadIdx.x;
    const int v = t & 63, jq = t >> 6;
    __shared__ float rnum[256];
    __shared__ float rden[4];
    const float* wr_ = wbuf + (size_t)(b * NH + h) * S;
    float dp = 0.f;
    for (int i = t; i < S; i += 256) dp += wr_[i];
#pragma unroll
    for (int off = 1; off < 64; off <<= 1) dp += __shfl_xor(dp, off);
    if ((t & 63) == 0) rden[t >> 6] = dp;
    const float* tr = tbuf + (size_t)(b * NH + h) * D;
    float np = 0.f;
    for (int j = jq * 256; j < jq * 256 + 256; ++j)
        np = fmaf(tr[j], Wv[(size_t)j * D + h * 64 + v], np);
    rnum[t] = np;
    __syncthreads();
    if (t < 64) {
        const float denom = rden[0] + rden[1] + rden[2] + rden[3];
        float num = rnum[v] + rnum[64 + v] + rnum[128 + v] + rnum[192 + v];
        num += denom * bv[h * 64 + v];
        ctx[(size_t)b * D + h * 64 + v] = num / (denom + 1e-6f);
    }
}

// ---------------- out = ctx @ Wo + bo ----------------
__global__ __launch_bounds__(256) void out_kernel(
        const float* __restrict__ ctx, const float* __restrict__ Wo,
        const float* __restrict__ bo, float* __restrict__ out)
{
    const int b = blockIdx.y;
    const int o = blockIdx.x * 256 + threadIdx.x;
    __shared__ float cl[D];
    for (int i = threadIdx.x; i < D; i += 256) cl[i] = ctx[(size_t)b * D + i];
    __syncthreads();
    float acc = bo[o];
    for (int j = 0; j < D; ++j) acc = fmaf(cl[j], Wo[(size_t)j * D + o], acc);
    out[(size_t)b * D + o] = acc;
}

extern "C" void kernel_launch(void* const* d_in, const int* in_sizes, int n_in,
                              void* d_out, int out_size, void* d_ws, size_t ws_size,
                              hipStream_t stream) {
    const float* y  = (const float*)d_in[0];
    const float* x  = (const float*)d_in[1];
    const float* Wq = (const float*)d_in[2];
    const float* bq = (const float*)d_in[3];
    const float* Wk = (const float*)d_in[4];
    const float* bk = (const float*)d_in[5];
    const float* Wv = (const float*)d_in[6];
    const float* bv = (const float*)d_in[7];
    const float* Wo = (const float*)d_in[8];
    const float* bo = (const float*)d_in[9];
    float* out = (float*)d_out;

    char* ws = (char*)d_ws;
    size_t off = 0;
    unsigned short* ybf  = (unsigned short*)(ws + off); off += (size_t)NB * S * D * 2;        // 128 MB
    unsigned short* WkT  = (unsigned short*)(ws + off); off += (size_t)D * D * 2;             // 2 MB
    float*          phiq = (float*)(ws + off);          off += (size_t)NB * D * 4;            // 64 KB
    float*          wbuf = (float*)(ws + off);          off += (size_t)NB * NH * S * 4;       // 4 MB
    float*          tpart= (float*)(ws + off);          off += (size_t)NSC * NB * NH * D * 4; // 16 MB
    float*          tbuf = (float*)(ws + off);          off += (size_t)NB * NH * D * 4;       // 1 MB
    float*          ctx  = (float*)(ws + off);          off += (size_t)NB * D * 4;            // 64 KB

    ybf_kernel <<<2048, 256, 0, stream>>>(y, ybf);
    phiq_kernel<<<dim3(4, NB), 256, 0, stream>>>(x, Wq, bq, phiq);
    wkt_kernel <<<dim3(32, 32), 256, 0, stream>>>(Wk, WkT);
    kgemm_kernel<<<2048, 256, 0, stream>>>(ybf, WkT, phiq, bk, wbuf);
    tpart_kernel<<<dim3(NSC, NB), 256, 0, stream>>>(ybf, wbuf, tpart);
    tred_kernel <<<1024, 256, 0, stream>>>(tpart, tbuf);
    ctx_kernel  <<<256, 256, 0, stream>>>(wbuf, tbuf, Wv, bv, ctx);
    out_kernel  <<<dim3(4, NB), 256, 0, stream>>>(ctx, Wo, bo, out);
}